// Round 1
// baseline (810.038 us; speedup 1.0000x reference)
//
#include <hip/hip_runtime.h>
#include <hip/hip_bf16.h>

typedef short s16x8 __attribute__((ext_vector_type(8)));
typedef float f32x4 __attribute__((ext_vector_type(4)));
typedef unsigned int u32x4 __attribute__((ext_vector_type(4)));
typedef unsigned int u32x2 __attribute__((ext_vector_type(2)));

__device__ __forceinline__ float b2f(unsigned short u) {
  unsigned int v = ((unsigned int)u) << 16;
  return __builtin_bit_cast(float, v);
}
__device__ __forceinline__ unsigned short f2b(float f) {
  __hip_bfloat16 h = __float2bfloat16(f);
  return __builtin_bit_cast(unsigned short, h);
}

// ---------------- cast x (fp32 -> bf16), 4 elems/thread ----------------
__global__ __launch_bounds__(256) void cast_x_kernel(const float* __restrict__ x,
                                                     unsigned short* __restrict__ xb) {
  int i = (blockIdx.x * 256 + threadIdx.x) * 4;
  f32x4 v = *(const f32x4*)(x + i);
  u32x2 o;
  o[0] = (unsigned)f2b(v[0]) | ((unsigned)f2b(v[1]) << 16);
  o[1] = (unsigned)f2b(v[2]) | ((unsigned)f2b(v[3]) << 16);
  *(u32x2*)(xb + i) = o;
}

// ---------------- transpose + cast W [K][N] fp32 -> Wt [N][K] bf16 ----------------
__global__ __launch_bounds__(256) void wtrans_kernel(const float* __restrict__ W,
                                                     unsigned short* __restrict__ Wt,
                                                     int K, int N) {
  __shared__ float tile[64][65];
  int n0 = blockIdx.x * 64, k0 = blockIdx.y * 64;
  int tx = threadIdx.x & 63, ty = threadIdx.x >> 6;
  #pragma unroll
  for (int i = ty; i < 64; i += 4) tile[i][tx] = W[(long)(k0 + i) * N + n0 + tx];
  __syncthreads();
  #pragma unroll
  for (int i = ty; i < 64; i += 4) Wt[(long)(n0 + i) * K + k0 + tx] = f2b(tile[tx][i]);
}

// ---------------- bf16 MFMA GEMM: C[M][N] = A[M][K] @ Bt[N][K]^T + bias ----------------
// 128x128 block tile, BK=32, 4 waves in 2x2, each wave 64x64 (4x4 MFMA 16x16x32 tiles).
template<bool BF16OUT>
__global__ __launch_bounds__(256) void gemm_bt_kernel(
    const unsigned short* __restrict__ A, int lda,
    const unsigned short* __restrict__ Bt0, int ldb,
    const float* __restrict__ bias,
    void* __restrict__ Cv, int N, int K,
    int rows_per_batch, long bstride) {
  __shared__ unsigned short a_lds[128 * 40];  // pad 32->40 to break bank conflicts
  __shared__ unsigned short b_lds[128 * 40];
  const int tid = threadIdx.x;
  const int lane = tid & 63, wid = tid >> 6;
  const int m0 = blockIdx.y * 128, n0 = blockIdx.x * 128;
  const int wm = (wid >> 1) * 64, wn = (wid & 1) * 64;
  const int fm = lane & 15, fq = lane >> 4;

  const unsigned short* Bt = Bt0;
  if (rows_per_batch) Bt += (long)(m0 / rows_per_batch) * bstride;

  f32x4 acc[4][4] = {};

  // staging: 512 chunks of 8 bf16 each per operand; thread takes chunks tid, tid+256
  const int r0 = tid >> 2;
  const int c0 = (tid & 3) * 8;
  const unsigned short* Aptr0 = A + (long)(m0 + r0) * lda + c0;
  const unsigned short* Aptr1 = Aptr0 + (long)64 * lda;
  const unsigned short* Bptr0 = Bt + (long)(n0 + r0) * ldb + c0;
  const unsigned short* Bptr1 = Bptr0 + (long)64 * ldb;
  unsigned short* a_st0 = &a_lds[r0 * 40 + c0];
  unsigned short* a_st1 = &a_lds[(r0 + 64) * 40 + c0];
  unsigned short* b_st0 = &b_lds[r0 * 40 + c0];
  unsigned short* b_st1 = &b_lds[(r0 + 64) * 40 + c0];

  for (int k0 = 0; k0 < K; k0 += 32) {
    u32x4 va0 = *(const u32x4*)(Aptr0 + k0);
    u32x4 va1 = *(const u32x4*)(Aptr1 + k0);
    u32x4 vb0 = *(const u32x4*)(Bptr0 + k0);
    u32x4 vb1 = *(const u32x4*)(Bptr1 + k0);
    __syncthreads();  // previous iteration's frag reads complete
    *(u32x4*)a_st0 = va0;
    *(u32x4*)a_st1 = va1;
    *(u32x4*)b_st0 = vb0;
    *(u32x4*)b_st1 = vb1;
    __syncthreads();
    s16x8 af[4], bfr[4];
    #pragma unroll
    for (int i = 0; i < 4; i++) {
      af[i]  = *(const s16x8*)&a_lds[(wm + i * 16 + fm) * 40 + fq * 8];
      bfr[i] = *(const s16x8*)&b_lds[(wn + i * 16 + fm) * 40 + fq * 8];
    }
    #pragma unroll
    for (int mi = 0; mi < 4; mi++)
      #pragma unroll
      for (int ni = 0; ni < 4; ni++)
        acc[mi][ni] = __builtin_amdgcn_mfma_f32_16x16x32_bf16(af[mi], bfr[ni], acc[mi][ni], 0, 0, 0);
  }

  // epilogue: D row = quad*4+r, col = lane&15
  #pragma unroll
  for (int ni = 0; ni < 4; ni++) {
    const int col = n0 + wn + ni * 16 + fm;
    const float bv = bias[col];
    #pragma unroll
    for (int mi = 0; mi < 4; mi++) {
      #pragma unroll
      for (int r = 0; r < 4; r++) {
        const long row = m0 + wm + mi * 16 + fq * 4 + r;
        const float v = acc[mi][ni][r] + bv;
        if (BF16OUT) ((unsigned short*)Cv)[row * N + col] = f2b(v);
        else         ((float*)Cv)[row * N + col] = v;
      }
    }
  }
}

// ---------------- A-pass: per (b,h), A_t[e][d] = sum_t (exp(q)/ksum_t? ...) ----------------
// Computes unnormalized A_t[e][d] = sum_t (exp(q[t,e]) * kinv[t]) * exp(k[t,d])
// and denom partials D[e] = sum_t exp(q[t,e]); per chunk of 1024 t. MFMA contraction.
__global__ __launch_bounds__(256) void apass_kernel(
    const unsigned short* __restrict__ qkv,
    float* __restrict__ Ap,   // [4][128][64e][64d]
    float* __restrict__ Dp) { // [4][8][1024]
  __shared__ unsigned short qs_lds[32 * 68];  // [t][e], row stride 68
  __shared__ unsigned short ks_lds[32 * 68];  // [t][d]
  __shared__ float dled[64];
  const int tid = threadIdx.x;
  const int chunk = blockIdx.x, g = blockIdx.y;
  const int b = g >> 4, h = g & 15;
  const int w = tid >> 6, lane = tid & 63;
  const int fm = lane & 15, fq = lane >> 4;
  const int tl = tid >> 3;        // staging row 0..31
  const int c0 = (tid & 7) * 8;   // staging col

  if (tid < 64) dled[tid] = 0.f;

  const long row0 = (long)(b * 4096 + chunk * 1024 + tl);
  const unsigned short* qptr = qkv + row0 * 3072 + h * 64 + c0;
  const unsigned short* kptr = qptr + 1024;

  f32x4 acc[4] = {};   // wave w owns e-rows [w*16, w*16+16), tiles ni=0..3 over d
  float dacc[8] = {};

  unsigned short* qst = &qs_lds[tl * 68 + c0];
  unsigned short* kst = &ks_lds[tl * 68 + c0];

  for (int ks = 0; ks < 32; ks++) {
    const long roff = (long)(ks * 32) * 3072;
    u32x4 qv = *(const u32x4*)(qptr + roff);
    u32x4 kv = *(const u32x4*)(kptr + roff);
    float qe[8], ke[8];
    #pragma unroll
    for (int i = 0; i < 4; i++) {
      qe[2*i]   = __expf(b2f((unsigned short)(qv[i] & 0xffffu)));
      qe[2*i+1] = __expf(b2f((unsigned short)(qv[i] >> 16)));
      ke[2*i]   = __expf(b2f((unsigned short)(kv[i] & 0xffffu)));
      ke[2*i+1] = __expf(b2f((unsigned short)(kv[i] >> 16)));
    }
    float p = 0.f;
    #pragma unroll
    for (int i = 0; i < 8; i++) p += ke[i];
    p += __shfl_xor(p, 1);
    p += __shfl_xor(p, 2);
    p += __shfl_xor(p, 4);          // 8 lanes sharing a t-row now all hold row sum
    const float kinv = 1.0f / p;
    unsigned int qpk[4], kpk[4];
    #pragma unroll
    for (int i = 0; i < 4; i++) {
      qpk[i] = (unsigned)f2b(qe[2*i] * kinv) | ((unsigned)f2b(qe[2*i+1] * kinv) << 16);
      kpk[i] = (unsigned)f2b(ke[2*i]) | ((unsigned)f2b(ke[2*i+1]) << 16);
      dacc[2*i]   += qe[2*i];
      dacc[2*i+1] += qe[2*i+1];
    }
    __syncthreads();   // previous iteration's frag reads complete
    u32x2 t0, t1;
    t0[0] = qpk[0]; t0[1] = qpk[1]; t1[0] = qpk[2]; t1[1] = qpk[3];
    *(u32x2*)qst = t0; *(u32x2*)(qst + 4) = t1;
    t0[0] = kpk[0]; t0[1] = kpk[1]; t1[0] = kpk[2]; t1[1] = kpk[3];
    *(u32x2*)kst = t0; *(u32x2*)(kst + 4) = t1;
    __syncthreads();
    s16x8 af;
    #pragma unroll
    for (int j = 0; j < 8; j++)
      af[j] = (short)qs_lds[(fq * 8 + j) * 68 + (w * 16 + fm)];
    #pragma unroll
    for (int ni = 0; ni < 4; ni++) {
      s16x8 bfr;
      #pragma unroll
      for (int j = 0; j < 8; j++)
        bfr[j] = (short)ks_lds[(fq * 8 + j) * 68 + (ni * 16 + fm)];
      acc[ni] = __builtin_amdgcn_mfma_f32_16x16x32_bf16(af, bfr, acc[ni], 0, 0, 0);
    }
  }
  float* ap = Ap + (long)(chunk * 128 + g) * 4096;
  #pragma unroll
  for (int ni = 0; ni < 4; ni++)
    #pragma unroll
    for (int r = 0; r < 4; r++)
      ap[(w * 16 + fq * 4 + r) * 64 + ni * 16 + fm] = acc[ni][r];
  #pragma unroll
  for (int i = 0; i < 8; i++) atomicAdd(&dled[c0 + i], dacc[i]);
  __syncthreads();
  if (tid < 64) Dp[(chunk * 8 + b) * 1024 + h * 64 + tid] = dled[tid];
}

// ---------------- M build: Mt[b][n][h*64+d] = sum_e (SCALE*A/den)[e][d] * Wproj[h*64+e][n] ----
__global__ __launch_bounds__(256) void mmake_kernel(
    const float* __restrict__ Ap,
    const float* __restrict__ Dp,
    const float* __restrict__ Wproj,
    unsigned short* __restrict__ Mt) {
  __shared__ float At[4096];  // [e][d]
  __shared__ float Wp[4096];  // [e][n]
  const int tid = threadIdx.x;
  const int n0 = blockIdx.x * 64;
  const int g = blockIdx.y;
  const int b = g >> 4, h = g & 15;
  #pragma unroll
  for (int j = 0; j < 16; j++) {
    int lin = tid + 256 * j;
    int e = lin >> 6, n = lin & 63;
    float s = 0.f, den = 0.f;
    #pragma unroll
    for (int c = 0; c < 4; c++) {
      s   += Ap[(long)(c * 128 + g) * 4096 + lin];
      den += Dp[(c * 8 + b) * 1024 + h * 64 + e];
    }
    At[lin] = 0.125f * s / den;   // SCALE = 64^-0.5
    Wp[lin] = Wproj[(long)(h * 64 + e) * 1024 + n0 + n];
  }
  __syncthreads();
  const int d = tid & 63, ng = tid >> 6;
  #pragma unroll
  for (int nn = 0; nn < 16; nn++) {
    const int n = ng * 16 + nn;
    float s = 0.f;
    #pragma unroll
    for (int e = 0; e < 64; e++)
      s = fmaf(At[e * 64 + d], Wp[e * 64 + n], s);
    Mt[((long)b << 20) + (long)(n0 + n) * 1024 + h * 64 + d] = f2b(s);
  }
}

// ---------------- launch ----------------
extern "C" void kernel_launch(void* const* d_in, const int* in_sizes, int n_in,
                              void* d_out, int out_size, void* d_ws, size_t ws_size,
                              hipStream_t stream) {
  const float* x     = (const float*)d_in[0];
  const float* Wqkv  = (const float*)d_in[1];
  const float* bqkv  = (const float*)d_in[2];
  const float* Wproj = (const float*)d_in[3];
  const float* bproj = (const float*)d_in[4];
  float* out = (float*)d_out;

  char* ws = (char*)d_ws;
  unsigned short* xb  = (unsigned short*)(ws + 0);           //  67,108,864 B
  unsigned short* wqt = (unsigned short*)(ws + 67108864);    //   6,291,456 B
  unsigned short* qkv = (unsigned short*)(ws + 73400320);    // 201,326,592 B
  float*          ap  = (float*)        (ws + 274726912);    //   8,388,608 B
  float*          dp  = (float*)        (ws + 283115520);    //     131,072 B
  unsigned short* mt  = (unsigned short*)(ws + 283246592);   //  16,777,216 B (end ~300MB)

  cast_x_kernel<<<dim3(32768), dim3(256), 0, stream>>>(x, xb);
  wtrans_kernel<<<dim3(48, 16), dim3(256), 0, stream>>>(Wqkv, wqt, 1024, 3072);
  gemm_bt_kernel<true><<<dim3(24, 256), dim3(256), 0, stream>>>(
      xb, 1024, wqt, 1024, bqkv, (void*)qkv, 3072, 1024, 0, 0);
  apass_kernel<<<dim3(4, 128), dim3(256), 0, stream>>>(qkv, ap, dp);
  mmake_kernel<<<dim3(16, 128), dim3(256), 0, stream>>>(ap, dp, Wproj, mt);
  gemm_bt_kernel<false><<<dim3(8, 256), dim3(256), 0, stream>>>(
      qkv + 2048, 3072, mt, 1024, bproj, (void*)out, 1024, 1024, 4096, 1048576);
}

// Round 2
// 718.828 us; speedup vs baseline: 1.1269x; 1.1269x over previous
//
#include <hip/hip_runtime.h>
#include <hip/hip_bf16.h>

typedef short s16x8 __attribute__((ext_vector_type(8)));
typedef short s16x4 __attribute__((ext_vector_type(4)));
typedef float f32x4 __attribute__((ext_vector_type(4)));
typedef unsigned int u32x4 __attribute__((ext_vector_type(4)));
typedef unsigned int u32x2 __attribute__((ext_vector_type(2)));

__device__ __forceinline__ float b2f(unsigned short u) {
  unsigned int v = ((unsigned int)u) << 16;
  return __builtin_bit_cast(float, v);
}
__device__ __forceinline__ unsigned short f2b(float f) {
  __hip_bfloat16 h = __float2bfloat16(f);
  return __builtin_bit_cast(unsigned short, h);
}
// async 16B global->LDS DMA; LDS dest = wave-uniform base + lane*16
__device__ __forceinline__ void async_ld16(const unsigned short* g, unsigned short* l) {
  __builtin_amdgcn_global_load_lds(
      (const __attribute__((address_space(1))) void*)g,
      (__attribute__((address_space(3))) void*)l, 16, 0, 0);
}

// ---------------- cast x (fp32 -> bf16), 4 elems/thread ----------------
__global__ __launch_bounds__(256) void cast_x_kernel(const float* __restrict__ x,
                                                     unsigned short* __restrict__ xb) {
  int i = (blockIdx.x * 256 + threadIdx.x) * 4;
  f32x4 v = *(const f32x4*)(x + i);
  u32x2 o;
  o[0] = (unsigned)f2b(v[0]) | ((unsigned)f2b(v[1]) << 16);
  o[1] = (unsigned)f2b(v[2]) | ((unsigned)f2b(v[3]) << 16);
  *(u32x2*)(xb + i) = o;
}

// ---------------- transpose + cast W [K][N] fp32 -> Wt [N][K] bf16 ----------------
__global__ __launch_bounds__(256) void wtrans_kernel(const float* __restrict__ W,
                                                     unsigned short* __restrict__ Wt,
                                                     int K, int N) {
  __shared__ float tile[64][65];
  int n0 = blockIdx.x * 64, k0 = blockIdx.y * 64;
  int tx = threadIdx.x & 63, ty = threadIdx.x >> 6;
  #pragma unroll
  for (int i = ty; i < 64; i += 4) tile[i][tx] = W[(long)(k0 + i) * N + n0 + tx];
  __syncthreads();
  #pragma unroll
  for (int i = ty; i < 64; i += 4) Wt[(long)(n0 + i) * K + k0 + tx] = f2b(tile[tx][i]);
}

// ---------------- bf16 MFMA GEMM: C[M][N] = A[M][K] @ Bt[N][K]^T + bias ----------------
// m97 structure: 128x128 tile, BK=32, global_load_lds width=16, XOR-swizzled LDS chunks.
// chunk (r, c_pos) holds global k-chunk c_pos ^ ((r>>1)&3); frag ds_read_b128 is 2-way max.
template<bool BF16OUT>
__global__ __launch_bounds__(256) void gemm_bt_kernel(
    const unsigned short* __restrict__ A, int lda,
    const unsigned short* __restrict__ Bt0, int ldb,
    const float* __restrict__ bias,
    void* __restrict__ Cv, int N, int K,
    int rows_per_batch, long bstride) {
  __shared__ unsigned short a_lds[128 * 32];
  __shared__ unsigned short b_lds[128 * 32];
  const int tid = threadIdx.x;
  const int lane = tid & 63, wid = tid >> 6;
  const int m0 = blockIdx.y * 128, n0 = blockIdx.x * 128;
  const int wm = (wid >> 1) * 64, wn = (wid & 1) * 64;
  const int fm = lane & 15, fq = lane >> 4;

  const unsigned short* Bt = Bt0;
  if (rows_per_batch) Bt += (long)(m0 / rows_per_batch) * bstride;

  f32x4 acc[4][4] = {};

  const unsigned short* gA[2];
  const unsigned short* gB[2];
  unsigned short* lA[2];
  unsigned short* lB[2];
  #pragma unroll
  for (int j = 0; j < 2; j++) {
    const int C = (wid * 2 + j) * 64 + lane;   // 16B chunk id 0..511
    const int r = C >> 2, cp = C & 3;
    const int cg = cp ^ ((r >> 1) & 3);        // global k-chunk this lane fetches
    gA[j] = A + (long)(m0 + r) * lda + cg * 8;
    gB[j] = Bt + (long)(n0 + r) * ldb + cg * 8;
    lA[j] = a_lds + (wid * 2 + j) * 512;       // wave-uniform
    lB[j] = b_lds + (wid * 2 + j) * 512;
  }
  const int swa = (fq ^ ((fm >> 1) & 3)) * 8;  // swizzled chunk for frag reads

  for (int k0 = 0; k0 < K; k0 += 32) {
    __syncthreads();                           // prev iter's frag reads done
    async_ld16(gA[0] + k0, lA[0]);
    async_ld16(gA[1] + k0, lA[1]);
    async_ld16(gB[0] + k0, lB[0]);
    async_ld16(gB[1] + k0, lB[1]);
    __syncthreads();                           // compiler emits vmcnt(0) before barrier
    s16x8 af[4], bfr[4];
    #pragma unroll
    for (int i = 0; i < 4; i++) {
      af[i]  = *(const s16x8*)&a_lds[(wm + i * 16 + fm) * 32 + swa];
      bfr[i] = *(const s16x8*)&b_lds[(wn + i * 16 + fm) * 32 + swa];
    }
    #pragma unroll
    for (int mi = 0; mi < 4; mi++)
      #pragma unroll
      for (int ni = 0; ni < 4; ni++)
        acc[mi][ni] = __builtin_amdgcn_mfma_f32_16x16x32_bf16(af[mi], bfr[ni], acc[mi][ni], 0, 0, 0);
  }

  // epilogue: D row = quad*4+r, col = lane&15
  #pragma unroll
  for (int ni = 0; ni < 4; ni++) {
    const int col = n0 + wn + ni * 16 + fm;
    const float bv = bias[col];
    #pragma unroll
    for (int mi = 0; mi < 4; mi++) {
      #pragma unroll
      for (int r = 0; r < 4; r++) {
        const long row = m0 + wm + mi * 16 + fq * 4 + r;
        const float v = acc[mi][ni][r] + bv;
        if (BF16OUT) ((unsigned short*)Cv)[row * N + col] = f2b(v);
        else         ((float*)Cv)[row * N + col] = v;
      }
    }
  }
}

// ---------------- A-pass ----------------
// Unnormalized A_t[e][d] = sum_t (exp(q[t,e]) * kinv[t]) * exp(k[t,d]) and
// denom partials D[e] = sum_t exp(q[t,e]); per chunk of 1024 t. MFMA contraction.
// LDS held TRANSPOSED ([e][t], stride 36) so frag assembly is ds_read_b64 pairs.
__global__ __launch_bounds__(256) void apass_kernel(
    const unsigned short* __restrict__ qkv,
    float* __restrict__ Ap,   // [4][128][64e][64d]
    float* __restrict__ Dp) { // [4][8][1024]
  __shared__ unsigned short qT[64 * 36 + 8];  // [e][t]
  __shared__ unsigned short kT[64 * 36 + 8];  // [d][t]
  __shared__ float dled[64];
  const int tid = threadIdx.x;
  const int chunk = blockIdx.x, g = blockIdx.y;
  const int b = g >> 4, h = g & 15;
  const int w = tid >> 6, lane = tid & 63;
  const int fm = lane & 15, fq = lane >> 4;
  const int tl = tid >> 3;        // staging row t 0..31
  const int c0 = (tid & 7) * 8;   // staging col e/d

  if (tid < 64) dled[tid] = 0.f;

  const long row0 = (long)(b * 4096 + chunk * 1024 + tl);
  const unsigned short* qptr = qkv + row0 * 3072 + h * 64 + c0;
  const unsigned short* kptr = qptr + 1024;

  f32x4 acc[4] = {};   // wave w owns e-rows [w*16, w*16+16), tiles ni over d
  float dacc[8] = {};

  for (int ks = 0; ks < 32; ks++) {
    const long roff = (long)(ks * 32) * 3072;
    u32x4 qv = *(const u32x4*)(qptr + roff);
    u32x4 kv = *(const u32x4*)(kptr + roff);
    float qe[8], ke[8];
    #pragma unroll
    for (int i = 0; i < 4; i++) {
      qe[2*i]   = __expf(b2f((unsigned short)(qv[i] & 0xffffu)));
      qe[2*i+1] = __expf(b2f((unsigned short)(qv[i] >> 16)));
      ke[2*i]   = __expf(b2f((unsigned short)(kv[i] & 0xffffu)));
      ke[2*i+1] = __expf(b2f((unsigned short)(kv[i] >> 16)));
    }
    float p = 0.f;
    #pragma unroll
    for (int i = 0; i < 8; i++) p += ke[i];
    p += __shfl_xor(p, 1);
    p += __shfl_xor(p, 2);
    p += __shfl_xor(p, 4);          // 8 lanes sharing a t-row now hold row sum
    const float kinv = 1.0f / p;
    #pragma unroll
    for (int i = 0; i < 8; i++) dacc[i] += qe[i];
    __syncthreads();   // prev iter's frag reads complete
    #pragma unroll
    for (int i = 0; i < 8; i++) {
      qT[(c0 + i) * 36 + tl] = f2b(qe[i] * kinv);
      kT[(c0 + i) * 36 + tl] = f2b(ke[i]);
    }
    __syncthreads();
    const int aoff = (w * 16 + fm) * 36 + fq * 8;
    s16x4 alo = *(const s16x4*)&qT[aoff];
    s16x4 ahi = *(const s16x4*)&qT[aoff + 4];
    s16x8 af = {alo[0], alo[1], alo[2], alo[3], ahi[0], ahi[1], ahi[2], ahi[3]};
    #pragma unroll
    for (int ni = 0; ni < 4; ni++) {
      const int boff = (ni * 16 + fm) * 36 + fq * 8;
      s16x4 blo = *(const s16x4*)&kT[boff];
      s16x4 bhi = *(const s16x4*)&kT[boff + 4];
      s16x8 bfr = {blo[0], blo[1], blo[2], blo[3], bhi[0], bhi[1], bhi[2], bhi[3]};
      acc[ni] = __builtin_amdgcn_mfma_f32_16x16x32_bf16(af, bfr, acc[ni], 0, 0, 0);
    }
  }
  float* ap = Ap + (long)(chunk * 128 + g) * 4096;
  #pragma unroll
  for (int ni = 0; ni < 4; ni++)
    #pragma unroll
    for (int r = 0; r < 4; r++)
      ap[(w * 16 + fq * 4 + r) * 64 + ni * 16 + fm] = acc[ni][r];
  #pragma unroll
  for (int i = 0; i < 8; i++) atomicAdd(&dled[c0 + i], dacc[i]);
  __syncthreads();
  if (tid < 64) Dp[(chunk * 8 + b) * 1024 + h * 64 + tid] = dled[tid];
}

// ---------------- M build: Mt[b][n][h*64+d] = sum_e (SCALE*A/den)[e][d] * Wproj[h*64+e][n] ----
__global__ __launch_bounds__(256) void mmake_kernel(
    const float* __restrict__ Ap,
    const float* __restrict__ Dp,
    const float* __restrict__ Wproj,
    unsigned short* __restrict__ Mt) {
  __shared__ float At[4096];  // [e][d]
  __shared__ float Wp[4096];  // [e][n]
  const int tid = threadIdx.x;
  const int n0 = blockIdx.x * 64;
  const int g = blockIdx.y;
  const int b = g >> 4, h = g & 15;
  #pragma unroll
  for (int j = 0; j < 16; j++) {
    int lin = tid + 256 * j;
    int e = lin >> 6, n = lin & 63;
    float s = 0.f, den = 0.f;
    #pragma unroll
    for (int c = 0; c < 4; c++) {
      s   += Ap[(long)(c * 128 + g) * 4096 + lin];
      den += Dp[(c * 8 + b) * 1024 + h * 64 + e];
    }
    At[lin] = 0.125f * s / den;   // SCALE = 64^-0.5
    Wp[lin] = Wproj[(long)(h * 64 + e) * 1024 + n0 + n];
  }
  __syncthreads();
  const int d = tid & 63, ng = tid >> 6;
  float a_reg[64];
  #pragma unroll
  for (int e = 0; e < 64; e++) a_reg[e] = At[e * 64 + d];
  #pragma unroll
  for (int nn = 0; nn < 16; nn++) {
    const int n = ng * 16 + nn;
    float s = 0.f;
    #pragma unroll
    for (int e = 0; e < 64; e++)
      s = fmaf(a_reg[e], Wp[e * 64 + n], s);   // Wp read is wave-uniform broadcast
    Mt[((long)b << 20) + (long)(n0 + n) * 1024 + h * 64 + d] = f2b(s);
  }
}

// ---------------- launch ----------------
extern "C" void kernel_launch(void* const* d_in, const int* in_sizes, int n_in,
                              void* d_out, int out_size, void* d_ws, size_t ws_size,
                              hipStream_t stream) {
  const float* x     = (const float*)d_in[0];
  const float* Wqkv  = (const float*)d_in[1];
  const float* bqkv  = (const float*)d_in[2];
  const float* Wproj = (const float*)d_in[3];
  const float* bproj = (const float*)d_in[4];
  float* out = (float*)d_out;

  char* ws = (char*)d_ws;
  unsigned short* xb  = (unsigned short*)(ws + 0);           //  67,108,864 B
  unsigned short* wqt = (unsigned short*)(ws + 67108864);    //   6,291,456 B
  unsigned short* qkv = (unsigned short*)(ws + 73400320);    // 201,326,592 B
  float*          ap  = (float*)        (ws + 274726912);    //   8,388,608 B
  float*          dp  = (float*)        (ws + 283115520);    //     131,072 B
  unsigned short* mt  = (unsigned short*)(ws + 283246592);   //  16,777,216 B (end ~300MB)

  cast_x_kernel<<<dim3(32768), dim3(256), 0, stream>>>(x, xb);
  wtrans_kernel<<<dim3(48, 16), dim3(256), 0, stream>>>(Wqkv, wqt, 1024, 3072);
  gemm_bt_kernel<true><<<dim3(24, 256), dim3(256), 0, stream>>>(
      xb, 1024, wqt, 1024, bqkv, (void*)qkv, 3072, 1024, 0, 0);
  apass_kernel<<<dim3(4, 128), dim3(256), 0, stream>>>(qkv, ap, dp);
  mmake_kernel<<<dim3(16, 128), dim3(256), 0, stream>>>(ap, dp, Wproj, mt);
  gemm_bt_kernel<false><<<dim3(8, 256), dim3(256), 0, stream>>>(
      qkv + 2048, 3072, mt, 1024, bproj, (void*)out, 1024, 1024, 4096, 1048576);
}